// Round 2
// baseline (975.463 us; speedup 1.0000x reference)
//
#include <hip/hip_runtime.h>
#include <hip/hip_bf16.h>

typedef __attribute__((ext_vector_type(8))) __bf16 bf16x8;
typedef __attribute__((ext_vector_type(4))) float f32x4;

__device__ inline unsigned short f2bf(float f) {
  unsigned int u = __float_as_uint(f);
  u += 0x7fffu + ((u >> 16) & 1u);   // RNE
  return (unsigned short)(u >> 16);
}

__device__ inline void glds16(const void* g, void* l) {
  __builtin_amdgcn_global_load_lds((const __attribute__((address_space(1))) void*)g,
                                   (__attribute__((address_space(3))) void*)l,
                                   16, 0, 0);
}

// ---------------------------------------------------------------------------
// elementwise fp32 -> bf16 cast (vectorized float4 -> 4x bf16)
__global__ __launch_bounds__(256) void cast_kernel(const float* __restrict__ in,
                                                   unsigned short* __restrict__ out,
                                                   int n4) {
  int i = blockIdx.x * 256 + threadIdx.x;
  if (i >= n4) return;
  float4 v = ((const float4*)in)[i];
  ushort4 o;
  o.x = f2bf(v.x); o.y = f2bf(v.y); o.z = f2bf(v.z); o.w = f2bf(v.w);
  ((ushort4*)out)[i] = o;
}

// ---------------------------------------------------------------------------
// transpose + cast: in fp32 [R][C] -> out bf16 [C][R]
__global__ __launch_bounds__(256) void transpose_cast(const float* __restrict__ in,
                                                      unsigned short* __restrict__ out,
                                                      int R, int C) {
  __shared__ float tile[32][33];
  int tx = threadIdx.x & 31, ty = threadIdx.x >> 5;
  int c = blockIdx.x * 32 + tx;
#pragma unroll
  for (int k = 0; k < 4; ++k) {
    int r = blockIdx.y * 32 + ty + k * 8;
    tile[ty + k * 8][tx] = in[(size_t)r * C + c];
  }
  __syncthreads();
  int rr = blockIdx.y * 32 + tx;
#pragma unroll
  for (int k = 0; k < 4; ++k) {
    int cc = blockIdx.x * 32 + ty + k * 8;
    out[(size_t)cc * R + rr] = f2bf(tile[tx][ty + k * 8]);
  }
}

// ---------------------------------------------------------------------------
// bf16 NT GEMM: C[M][N] = A[M][K] * Bt[N][K]^T  (+bias, per-mode epilogue)
// tile 128x64, BK=32, 4 waves, mfma_f32_16x16x32_bf16
// MODE 0: out bf16 -> heads layout [B][NH][L][64]    (q,k)
// MODE 1: out bf16 -> transposed  [B][NH][64][L]     (v)
// MODE 2: out fp32 = acc + bias + resid              (proj, ffn2)
// MODE 3: out bf16 = relu(acc + bias)                (ffn1)
template <int MODE>
__global__ __launch_bounds__(256) void gemm_bt(
    const unsigned short* __restrict__ A, const unsigned short* __restrict__ Bt,
    int M, int N, int K,
    const float* __restrict__ bias,
    float* __restrict__ outf, unsigned short* __restrict__ outb,
    const float* __restrict__ resid, int lshift, int L) {
  __shared__ __attribute__((aligned(16))) unsigned short As[128 * 32];
  __shared__ __attribute__((aligned(16))) unsigned short Bs[64 * 32];
  const int tid = threadIdx.x;
  const int l = tid & 63;
  const int lr = l & 15, lc = l >> 4;
  const int w = tid >> 6;
  const int wrow = (w >> 1) << 6;   // 0 / 64
  const int wcol = (w & 1) << 5;    // 0 / 32
  const long bm0 = (long)blockIdx.x * 128;
  const long bn0 = (long)blockIdx.y * 64;

  f32x4 acc[4][2];
#pragma unroll
  for (int m = 0; m < 4; ++m)
#pragma unroll
    for (int n = 0; n < 2; ++n) acc[m][n] = f32x4{0.f, 0.f, 0.f, 0.f};

  // staging address precompute (chunk-of-8-elem XOR swizzle: p ^= (row>>1)&3)
  const int r0 = tid >> 2, p0 = tid & 3;
  const int c1 = tid + 256;
  const int r1 = c1 >> 2, p1 = c1 & 3;
  const unsigned short* a0 = A + (bm0 + r0) * K + ((p0 ^ ((r0 >> 1) & 3)) << 3);
  const unsigned short* a1 = A + (bm0 + r1) * K + ((p1 ^ ((r1 >> 1) & 3)) << 3);
  const unsigned short* b0 = Bt + (bn0 + r0) * K + ((p0 ^ ((r0 >> 1) & 3)) << 3);

  for (int k0 = 0; k0 < K; k0 += 32) {
    glds16(a0 + k0, &As[tid * 8]);
    glds16(a1 + k0, &As[c1 * 8]);
    glds16(b0 + k0, &Bs[tid * 8]);
    __syncthreads();
    bf16x8 a[4], b[2];
#pragma unroll
    for (int m = 0; m < 4; ++m) {
      int row = wrow + m * 16 + lr;
      a[m] = *(const bf16x8*)&As[row * 32 + ((lc ^ ((row >> 1) & 3)) << 3)];
    }
#pragma unroll
    for (int n = 0; n < 2; ++n) {
      int row = wcol + n * 16 + lr;
      b[n] = *(const bf16x8*)&Bs[row * 32 + ((lc ^ ((row >> 1) & 3)) << 3)];
    }
#pragma unroll
    for (int m = 0; m < 4; ++m)
#pragma unroll
      for (int n = 0; n < 2; ++n)
        acc[m][n] = __builtin_amdgcn_mfma_f32_16x16x32_bf16(a[m], b[n], acc[m][n], 0, 0, 0);
    __syncthreads();
  }

  // epilogue: C/D layout col=lane&15, row=(lane>>4)*4+r  [measured m89/m91]
#pragma unroll
  for (int m = 0; m < 4; ++m)
#pragma unroll
    for (int n = 0; n < 2; ++n)
#pragma unroll
      for (int r = 0; r < 4; ++r) {
        const int gm = (int)bm0 + wrow + m * 16 + lc * 4 + r;
        const int gn = (int)bn0 + wcol + n * 16 + lr;
        float val = acc[m][n][r] + bias[gn];
        if constexpr (MODE == 0) {
          const int bb = gm >> lshift, rl = gm & (L - 1);
          const int hh = gn >> 6, dd = gn & 63;
          outb[((((size_t)bb * 16 + hh) * L + rl) << 6) + dd] = f2bf(val);
        } else if constexpr (MODE == 1) {
          const int bb = gm >> lshift, rl = gm & (L - 1);
          const int hh = gn >> 6, dd = gn & 63;
          outb[(((size_t)bb * 16 + hh) * 64 + dd) * L + rl] = f2bf(val);
        } else if constexpr (MODE == 2) {
          const size_t idx = (size_t)gm * N + gn;
          outf[idx] = val + resid[idx];
        } else {
          outb[(size_t)gm * N + gn] = f2bf(fmaxf(val, 0.f));
        }
      }
}

// ---------------------------------------------------------------------------
// fused sigmoid attention: per block = one (b, h, 128-row q tile)
// q [B][NH][Lq][64] bf16, k [B][NH][Lk][64] bf16, v^T [B][NH][64][Lk] bf16
// writes att_map fp32 [B][NH][Lq][Lk] and atted bf16 [B*Lq][H]
__global__ __launch_bounds__(256) void attn_kernel(
    const unsigned short* __restrict__ qb, const unsigned short* __restrict__ kb,
    const unsigned short* __restrict__ vtb,
    float* __restrict__ amap_out, unsigned short* __restrict__ atted) {
  constexpr int Lq = 1024, Lk = 2048, DH = 64, NH = 16;
  constexpr int PS = 152;  // att LDS row stride (bf16 elems): 304B, 16B-aligned, 2-way banks
  __shared__ __attribute__((aligned(16))) unsigned short Qs[128 * 64];
  __shared__ __attribute__((aligned(16))) unsigned short KVs[128 * 64];
  __shared__ __attribute__((aligned(16))) unsigned short Ps[128 * PS];
  const int tid = threadIdx.x;
  const int l = tid & 63, w = tid >> 6;
  const int lr = l & 15, lc = l >> 4;
  const int wr = (w >> 1) * 64;   // q offset
  const int wc = (w & 1) * 64;    // key offset (QK^T)
  const int pwc = (w & 1) * 32;   // d offset (PV)
  const int qt = blockIdx.x, h = blockIdx.y, b = blockIdx.z;
  const unsigned short* qhead = qb + ((size_t)(b * NH + h) * Lq + qt * 128) * DH;
  const unsigned short* khead = kb + (size_t)(b * NH + h) * Lk * DH;
  const unsigned short* vhead = vtb + (size_t)(b * NH + h) * DH * Lk;
  float* amap = amap_out + ((size_t)(b * NH + h) * Lq + qt * 128) * Lk;

  // stage Q once: 128x64 bf16, chunk swizzle p ^= row&7
#pragma unroll
  for (int i = 0; i < 4; ++i) {
    int c = i * 256 + tid;
    int row = c >> 3, p = c & 7;
    glds16(qhead + row * DH + ((p ^ (row & 7)) << 3), &Qs[c * 8]);
  }

  f32x4 pacc[4][2];
#pragma unroll
  for (int m = 0; m < 4; ++m)
#pragma unroll
    for (int n = 0; n < 2; ++n) pacc[m][n] = f32x4{0.f, 0.f, 0.f, 0.f};

  for (int kt = 0; kt < 16; ++kt) {
    // stage K tile [128 keys][64]
    const unsigned short* ksrc = khead + (size_t)kt * 128 * DH;
#pragma unroll
    for (int i = 0; i < 4; ++i) {
      int c = i * 256 + tid;
      int row = c >> 3, p = c & 7;
      glds16(ksrc + row * DH + ((p ^ (row & 7)) << 3), &KVs[c * 8]);
    }
    __syncthreads();

    // QK^T: 128q x 128k, K-dim 64 (2 mfma steps)
    f32x4 sacc[4][4];
#pragma unroll
    for (int m = 0; m < 4; ++m)
#pragma unroll
      for (int n = 0; n < 4; ++n) sacc[m][n] = f32x4{0.f, 0.f, 0.f, 0.f};
    bf16x8 aq[4][2], bk[4][2];
#pragma unroll
    for (int m = 0; m < 4; ++m)
#pragma unroll
      for (int s = 0; s < 2; ++s) {
        int row = wr + m * 16 + lr;
        int g = s * 4 + lc;
        aq[m][s] = *(const bf16x8*)&Qs[row * 64 + ((g ^ (row & 7)) << 3)];
      }
#pragma unroll
    for (int n = 0; n < 4; ++n)
#pragma unroll
      for (int s = 0; s < 2; ++s) {
        int row = wc + n * 16 + lr;
        int g = s * 4 + lc;
        bk[n][s] = *(const bf16x8*)&KVs[row * 64 + ((g ^ (row & 7)) << 3)];
      }
#pragma unroll
    for (int m = 0; m < 4; ++m)
#pragma unroll
      for (int n = 0; n < 4; ++n)
#pragma unroll
        for (int s = 0; s < 2; ++s)
          sacc[m][n] = __builtin_amdgcn_mfma_f32_16x16x32_bf16(aq[m][s], bk[n][s], sacc[m][n], 0, 0, 0);

    // sigmoid, write att_map (global fp32) + Ps (LDS bf16)
    float* amap_t = amap + kt * 128;
#pragma unroll
    for (int m = 0; m < 4; ++m)
#pragma unroll
      for (int n = 0; n < 4; ++n)
#pragma unroll
        for (int r = 0; r < 4; ++r) {
          int qrow = wr + m * 16 + lc * 4 + r;
          int kcol = wc + n * 16 + lr;
          float att = 1.0f / (1.0f + __expf(-0.125f * sacc[m][n][r]));
          amap_t[(size_t)qrow * Lk + kcol] = att;
          Ps[qrow * PS + kcol] = f2bf(att);
        }
    __syncthreads();

    // stage V tile: LDS [64 d][128 k], chunk swizzle p ^= d&15
    const unsigned short* vsrc = vhead + kt * 128;
#pragma unroll
    for (int i = 0; i < 4; ++i) {
      int c = i * 256 + tid;
      int d = c >> 4, p = c & 15;
      glds16(vsrc + (size_t)d * Lk + ((p ^ (d & 15)) << 3), &KVs[c * 8]);
    }
    __syncthreads();

    // PV: atted[128q][64d] += att[128q][128k] * V[128k][64d]
    bf16x8 pa[4][4], pb[2][4];
#pragma unroll
    for (int m = 0; m < 4; ++m)
#pragma unroll
      for (int s = 0; s < 4; ++s)
        pa[m][s] = *(const bf16x8*)&Ps[(wr + m * 16 + lr) * PS + s * 32 + lc * 8];
#pragma unroll
    for (int n = 0; n < 2; ++n)
#pragma unroll
      for (int s = 0; s < 4; ++s) {
        int d = pwc + n * 16 + lr;
        int g = s * 4 + lc;
        pb[n][s] = *(const bf16x8*)&KVs[d * 128 + ((g ^ (d & 15)) << 3)];
      }
#pragma unroll
    for (int m = 0; m < 4; ++m)
#pragma unroll
      for (int n = 0; n < 2; ++n)
#pragma unroll
        for (int s = 0; s < 4; ++s)
          pacc[m][n] = __builtin_amdgcn_mfma_f32_16x16x32_bf16(pa[m][s], pb[n][s], pacc[m][n], 0, 0, 0);
    __syncthreads();
  }

  // write atted bf16 into [B*Lq][H] (A-operand of the Wm GEMM)
#pragma unroll
  for (int m = 0; m < 4; ++m)
#pragma unroll
    for (int n = 0; n < 2; ++n)
#pragma unroll
      for (int r = 0; r < 4; ++r) {
        int q = wr + m * 16 + lc * 4 + r;
        int dd = pwc + n * 16 + lr;
        atted[(size_t)(b * Lq + qt * 128 + q) * 1024 + h * 64 + dd] = f2bf(pacc[m][n][r]);
      }
}

// ---------------------------------------------------------------------------
// LayerNorm row kernel (H=1024): torch-style  g*(x-mean)/(std+eps)+b, std ddof=1
__global__ __launch_bounds__(256) void ln_kernel(
    const float* __restrict__ in, const float* __restrict__ gw,
    const float* __restrict__ bw, float* __restrict__ outf,
    unsigned short* __restrict__ outb) {
  __shared__ float red[8];
  const int row = blockIdx.x, tid = threadIdx.x;
  const float4 v = ((const float4*)(in + (size_t)row * 1024))[tid];
  float s = v.x + v.y + v.z + v.w;
#pragma unroll
  for (int o = 32; o >= 1; o >>= 1) s += __shfl_down(s, o, 64);
  if ((tid & 63) == 0) red[tid >> 6] = s;
  __syncthreads();
  const float mean = (red[0] + red[1] + red[2] + red[3]) * (1.0f / 1024.0f);
  const float dx = v.x - mean, dy = v.y - mean, dz = v.z - mean, dw = v.w - mean;
  float sq = dx * dx + dy * dy + dz * dz + dw * dw;
#pragma unroll
  for (int o = 32; o >= 1; o >>= 1) sq += __shfl_down(sq, o, 64);
  if ((tid & 63) == 0) red[4 + (tid >> 6)] = sq;
  __syncthreads();
  const float var = (red[4] + red[5] + red[6] + red[7]) * (1.0f / 1023.0f);
  const float inv = 1.0f / (sqrtf(var) + 1e-6f);
  const float4 g4 = ((const float4*)gw)[tid];
  const float4 b4 = ((const float4*)bw)[tid];
  float4 o;
  o.x = g4.x * dx * inv + b4.x;
  o.y = g4.y * dy * inv + b4.y;
  o.z = g4.z * dz * inv + b4.z;
  o.w = g4.w * dw * inv + b4.w;
  ((float4*)(outf + (size_t)row * 1024))[tid] = o;
  if (outb) {
    ushort4 ob;
    ob.x = f2bf(o.x); ob.y = f2bf(o.y); ob.z = f2bf(o.z); ob.w = f2bf(o.w);
    *(ushort4*)(outb + (size_t)row * 1024 + tid * 4) = ob;
  }
}

// ---------------------------------------------------------------------------
extern "C" void kernel_launch(void* const* d_in, const int* in_sizes, int n_in,
                              void* d_out, int out_size, void* d_ws, size_t ws_size,
                              hipStream_t stream) {
  const float* x  = (const float*)d_in[0];
  const float* y  = (const float*)d_in[1];
  const float* Wq = (const float*)d_in[2];
  const float* bq = (const float*)d_in[3];
  const float* Wk = (const float*)d_in[4];
  const float* bk = (const float*)d_in[5];
  const float* Wv = (const float*)d_in[6];
  const float* bv = (const float*)d_in[7];
  const float* Wm = (const float*)d_in[8];
  const float* bm = (const float*)d_in[9];
  const float* W1 = (const float*)d_in[10];
  const float* b1 = (const float*)d_in[11];
  const float* W2 = (const float*)d_in[12];
  const float* b2 = (const float*)d_in[13];
  const float* g1 = (const float*)d_in[14];
  const float* be1 = (const float*)d_in[15];
  const float* g2 = (const float*)d_in[16];
  const float* be2 = (const float*)d_in[17];

  float* out = (float*)d_out;
  float* amap = out + (size_t)4 * 1024 * 1024;

  char* ws = (char*)d_ws;
  unsigned short* xb  = (unsigned short*)(ws);                 // 8 MB, dead after q-GEMM
  unsigned short* yb  = (unsigned short*)(ws + 8388608);       // 16 MB, dead after v-GEMM
  unsigned short* Wqt = (unsigned short*)(ws + 25165824);      // 16 MB total weights
  unsigned short* Wkt = Wqt + 1024 * 1024;
  unsigned short* Wvt = Wkt + 1024 * 1024;
  unsigned short* Wmt = Wvt + 1024 * 1024;
  unsigned short* W1t = Wmt + 1024 * 1024;                     // [2048][1024]
  unsigned short* W2t = W1t + 2048 * 1024;                     // [1024][2048]
  unsigned short* qb  = (unsigned short*)(ws + 41943040);      // 8 MB
  unsigned short* kb  = (unsigned short*)(ws + 50331648);      // 16 MB
  unsigned short* vtb = (unsigned short*)(ws + 67108864);      // 16 MB
  unsigned short* attedb = (unsigned short*)(ws + 83886080);   // 8 MB  (total 92.3 MB)
  // aliases of dead buffers:
  float* h1 = (float*)(ws + 50331648);            // alias kb  (written after attn)
  float* hf = (float*)(ws + 67108864);            // alias vtb (written by LN1)
  unsigned short* hb = (unsigned short*)(ws);     // alias xb  (LN1 bf16 out)
  unsigned short* ffnb = (unsigned short*)(ws + 8388608);  // alias yb (FFN1 out)
  float* h2 = (float*)(ws + 50331648);            // alias h1  (h1 dead after LN1)

  cast_kernel<<<4096, 256, 0, stream>>>(x, xb, 1024 * 1024);
  cast_kernel<<<8192, 256, 0, stream>>>(y, yb, 2 * 1024 * 1024);
  transpose_cast<<<dim3(32, 32), 256, 0, stream>>>(Wq, Wqt, 1024, 1024);
  transpose_cast<<<dim3(32, 32), 256, 0, stream>>>(Wk, Wkt, 1024, 1024);
  transpose_cast<<<dim3(32, 32), 256, 0, stream>>>(Wv, Wvt, 1024, 1024);
  transpose_cast<<<dim3(32, 32), 256, 0, stream>>>(Wm, Wmt, 1024, 1024);
  transpose_cast<<<dim3(64, 32), 256, 0, stream>>>(W1, W1t, 1024, 2048);
  transpose_cast<<<dim3(32, 64), 256, 0, stream>>>(W2, W2t, 2048, 1024);

  gemm_bt<0><<<dim3(32, 16), 256, 0, stream>>>(xb, Wqt, 4096, 1024, 1024, bq, nullptr, qb,  nullptr, 10, 1024);
  gemm_bt<0><<<dim3(64, 16), 256, 0, stream>>>(yb, Wkt, 8192, 1024, 1024, bk, nullptr, kb,  nullptr, 11, 2048);
  gemm_bt<1><<<dim3(64, 16), 256, 0, stream>>>(yb, Wvt, 8192, 1024, 1024, bv, nullptr, vtb, nullptr, 11, 2048);

  attn_kernel<<<dim3(8, 16, 4), 256, 0, stream>>>(qb, kb, vtb, amap, attedb);

  gemm_bt<2><<<dim3(32, 16), 256, 0, stream>>>(attedb, Wmt, 4096, 1024, 1024, bm, h1, nullptr, x, 0, 0);
  ln_kernel<<<4096, 256, 0, stream>>>(h1, g1, be1, hf, hb);
  gemm_bt<3><<<dim3(32, 32), 256, 0, stream>>>(hb, W1t, 4096, 2048, 1024, b1, nullptr, ffnb, nullptr, 0, 0);
  gemm_bt<2><<<dim3(32, 16), 256, 0, stream>>>(ffnb, W2t, 4096, 1024, 2048, b2, h2, nullptr, hf, 0, 0);
  ln_kernel<<<4096, 256, 0, stream>>>(h2, g2, be2, out, nullptr);
}